// Round 5
// baseline (110.982 us; speedup 1.0000x reference)
//
#include <hip/hip_runtime.h>

#define HW_    12544   // 112*112
#define W_     112
#define C_     128
#define OHW_   3136    // 56*56
#define OW_    56
#define NCHUNK 49      // chunks per batch sample (8192 float4 each)

// ---------------- Pass 1: per-(batch,chunk) phase sums of squares ----------------
__global__ __launch_bounds__(512) void phase_norms(const float* __restrict__ inp,
                                                   float* __restrict__ part) {
    const int b = blockIdx.y;
    const float4* src = (const float4*)(inp + (size_t)b * (C_ * HW_));
    const unsigned tid = threadIdx.x;
    const unsigned base = blockIdx.x * 8192u + tid;

    float s[4] = {0.f, 0.f, 0.f, 0.f};
#pragma unroll
    for (int k = 0; k < 16; ++k) {
        unsigned g = base + k * 512u;
        float4 v = src[g];
        unsigned hp = (g / 28u) & 1u;          // 28 float4 per row
        s[hp]      += v.x * v.x + v.z * v.z;   // even w -> phases 0/1
        s[hp + 2u] += v.y * v.y + v.w * v.w;   // odd  w -> phases 2/3
    }
#pragma unroll
    for (int p = 0; p < 4; ++p) {
        float v = s[p];
        for (int off = 32; off > 0; off >>= 1) v += __shfl_down(v, off);
        s[p] = v;
    }
    __shared__ float bs[8][4];
    const unsigned wid = tid >> 6;
    if ((tid & 63u) == 0u) {
#pragma unroll
        for (int p = 0; p < 4; ++p) bs[wid][p] = s[p];
    }
    __syncthreads();
    if (tid < 4) {
        float v = 0.f;
#pragma unroll
        for (int w = 0; w < 8; ++w) v += bs[w][tid];
        part[((size_t)b * NCHUNK + blockIdx.x) * 4 + tid] = v;
    }
}

// ---------------- Pass 1.5: finalize 32 argmax indices ----------------
__global__ __launch_bounds__(128) void finalize_idx(const float* __restrict__ part,
                                                    int* __restrict__ pidx) {
    const int t = threadIdx.x;            // 128 = 32 batches x 4 phases
    const int b = t >> 2, p = t & 3;
    float s = 0.f;
    for (int c = 0; c < NCHUNK; ++c) s += part[b * (NCHUNK * 4) + c * 4 + p];
    const int g = t & ~3;
    const float v0 = __shfl(s, g + 0), v1 = __shfl(s, g + 1);
    const float v2 = __shfl(s, g + 2), v3 = __shfl(s, g + 3);
    if (p == 0) {
        int idx = 0; float best = v0;
        if (v1 > best) { best = v1; idx = 1; }
        if (v2 > best) { best = v2; idx = 2; }
        if (v3 > best) { best = v3; idx = 3; }
        pidx[b] = idx;
    }
}

// ---------------- Pass 2: pure-gather blur + select. No LDS, no barriers. ----------------
// Thread = one 1x8 output strip. task g -> (bc, oh, s); s fast across lanes
// (coalesced). Per input row: 6 independent float4 (24 floats), static y indices.
__global__ __launch_bounds__(256) void blur_select(const float* __restrict__ inp,
                                                   const int* __restrict__ pidx,
                                                   float* __restrict__ out) {
    const int g  = blockIdx.x * 256 + threadIdx.x;   // 0 .. 4096*392-1 exactly
    const int bc = g / 392;
    const int r  = g - bc * 392;
    const int oh = r / 7;
    const int s  = r - oh * 7;
    const int ph = pidx[bc >> 7];
    const int dr = ph & 1, dc = ph >> 1;
    const float* P = inp + (size_t)bc * HW_;

    // load base (float4 index): s=0 -> 0, s=1..5 -> 4s-1, s=6 -> 22. Never OOB.
    const int base4 = (s == 0) ? 0 : ((s == 6) ? 22 : 4 * s - 1);
    const int jb = 2 * oh + dr - 1;

    float acc[8] = {0.f, 0.f, 0.f, 0.f, 0.f, 0.f, 0.f, 0.f};

#pragma unroll
    for (int k = 0; k < 4; ++k) {
        int j = jb + k;
        int aj = j < 0 ? -j : j;
        j = aj < 222 - aj ? aj : 222 - aj;
        const float4* rp = (const float4*)(P + j * W_) + base4;
        const float4 v0 = rp[0], v1 = rp[1], v2 = rp[2];
        const float4 v3 = rp[3], v4 = rp[4], v5 = rp[5];
        float y[24] = {v0.x, v0.y, v0.z, v0.w, v1.x, v1.y, v1.z, v1.w,
                       v2.x, v2.y, v2.z, v2.w, v3.x, v3.y, v3.z, v3.w,
                       v4.x, v4.y, v4.z, v4.w, v5.x, v5.y, v5.z, v5.w};
        float h[8];
        if (s == 0) {                       // colbase = 0
            if (dc == 0) {
                h[0] = 3.f * y[0] + 4.f * y[1] + y[2];  // cols -1,0,1,2 ; x(-1)=x(1)
#pragma unroll
                for (int u = 1; u < 8; ++u)
                    h[u] = (y[2*u-1] + y[2*u+2]) + 3.f * (y[2*u] + y[2*u+1]);
            } else {
#pragma unroll
                for (int u = 0; u < 8; ++u)
                    h[u] = (y[2*u] + y[2*u+3]) + 3.f * (y[2*u+1] + y[2*u+2]);
            }
        } else if (s == 6) {                // colbase = 88
            if (dc == 0) {
#pragma unroll
                for (int u = 0; u < 7; ++u)
                    h[u] = (y[2*u+7] + y[2*u+10]) + 3.f * (y[2*u+8] + y[2*u+9]);
            } else {
#pragma unroll
                for (int u = 0; u < 7; ++u)
                    h[u] = (y[2*u+8] + y[2*u+11]) + 3.f * (y[2*u+9] + y[2*u+10]);
            }
            h[7] = y[21] + 4.f * y[22] + 3.f * y[23];   // reflect at cols 112/113
        } else {                            // colbase = 16s-4
            if (dc == 0) {
#pragma unroll
                for (int u = 0; u < 8; ++u)
                    h[u] = (y[2*u+3] + y[2*u+6]) + 3.f * (y[2*u+4] + y[2*u+5]);
            } else {
#pragma unroll
                for (int u = 0; u < 8; ++u)
                    h[u] = (y[2*u+4] + y[2*u+7]) + 3.f * (y[2*u+5] + y[2*u+6]);
            }
        }
        const float wk = (k == 1 || k == 2) ? 3.f : 1.f;
#pragma unroll
        for (int u = 0; u < 8; ++u) acc[u] += wk * h[u];
    }

    float* o = out + (size_t)bc * OHW_ + oh * OW_ + 8 * s;
    *(float4*)o = make_float4(acc[0] * 0.015625f, acc[1] * 0.015625f,
                              acc[2] * 0.015625f, acc[3] * 0.015625f);
    *(float4*)(o + 4) = make_float4(acc[4] * 0.015625f, acc[5] * 0.015625f,
                                    acc[6] * 0.015625f, acc[7] * 0.015625f);
}

extern "C" void kernel_launch(void* const* d_in, const int* in_sizes, int n_in,
                              void* d_out, int out_size, void* d_ws, size_t ws_size,
                              hipStream_t stream) {
    const float* inp = (const float*)d_in[0];
    float* part = (float*)d_ws;                       // 32*49*4 floats = 25088 B
    int* pidx = (int*)((char*)d_ws + 32 * NCHUNK * 4 * sizeof(float));
    phase_norms<<<dim3(NCHUNK, 32), 512, 0, stream>>>(inp, part);
    finalize_idx<<<1, 128, 0, stream>>>(part, pidx);
    blur_select<<<6272, 256, 0, stream>>>(inp, pidx, (float*)d_out);
}